// Round 19
// baseline (193.349 us; speedup 1.0000x reference)
//
#include <hip/hip_runtime.h>
#include <math.h>

#define N_NODES 100000
#define IN_DIM 64
#define HID 128
#define HID2 64
#define N_EDGES 1600000
#define BN_EPS 1e-5f

// bucketing: 128 dst nodes per bucket
#define NPB 128
#define NB 782            // ceil(100000/128)
#define BIN_BLOCKS 391
#define BIN_CHUNK 4096    // 391*4096 >= 1.6M
#define SORT_CAP 4096     // bucket capacity for LDS sort (mean 2048, sigma ~45)
#define CAST_BLOCKS 6250  // N_NODES*16/256

typedef __attribute__((ext_vector_type(8))) __bf16 bf16x8;
typedef __attribute__((ext_vector_type(4))) float f32x4;
typedef __attribute__((ext_vector_type(2))) float f32x2;
typedef __attribute__((ext_vector_type(8))) unsigned short u16x8;

__device__ __forceinline__ unsigned short f2bf(float f) {
    unsigned int u = __builtin_bit_cast(unsigned int, f);
    u += 0x7fffu + ((u >> 16) & 1u);          // round-to-nearest-even
    return (unsigned short)(u >> 16);
}

// accumulate 8 fp8 e4m3 (one uint2) into 8 fp32 via HW converter
__device__ __forceinline__ void accum_fp8x8(float a[8], uint2 v) {
    f32x2 p0 = __builtin_amdgcn_cvt_pk_f32_fp8((int)v.x, false);
    f32x2 p1 = __builtin_amdgcn_cvt_pk_f32_fp8((int)v.x, true);
    f32x2 p2 = __builtin_amdgcn_cvt_pk_f32_fp8((int)v.y, false);
    f32x2 p3 = __builtin_amdgcn_cvt_pk_f32_fp8((int)v.y, true);
    a[0] += p0.x; a[1] += p0.y; a[2] += p1.x; a[3] += p1.y;
    a[4] += p2.x; a[5] += p2.y; a[6] += p3.x; a[7] += p3.y;
}

// accumulate 16 fp8 e4m3 (one uint4) into 16 fp32
__device__ __forceinline__ void accum_fp8x16(float a[16], uint4 v) {
    unsigned int w[4] = {v.x, v.y, v.z, v.w};
    #pragma unroll
    for (int k = 0; k < 4; ++k) {
        f32x2 lo = __builtin_amdgcn_cvt_pk_f32_fp8((int)w[k], false);
        f32x2 hi = __builtin_amdgcn_cvt_pk_f32_fp8((int)w[k], true);
        a[4*k+0] += lo.x; a[4*k+1] += lo.y;
        a[4*k+2] += hi.x; a[4*k+3] += hi.y;
    }
}

// ---------------------------------------------------------------------------
// prep_all: one kernel for all prep work.
//   blocks [0,16):              pack W1c/W2c into bf16 MFMA B-fragment order
//   blocks [16,16+CAST_BLOCKS): cast x -> bf16 (xbf) AND fp8 (x8 table)
//   last block:                 zero bucketTotal
// ---------------------------------------------------------------------------
__global__ __launch_bounds__(256) void prep_all(
    const float* __restrict__ x,
    const float* __restrict__ W1l, const float* __restrict__ W1r,
    const float* __restrict__ W2l, const float* __restrict__ W2r,
    unsigned short* __restrict__ Wf1, unsigned short* __restrict__ Wf2,
    unsigned short* __restrict__ xbf,    // [N,64] bf16
    unsigned char* __restrict__ x8,      // [N,64] fp8
    int* __restrict__ bucketTotal)
{
    const int bid = blockIdx.x;
    if (bid < 16) {
        int task = bid * 4 + (threadIdx.x >> 6);   // 0..63
        int lane = threadIdx.x & 63;
        int m  = task >> 5;          // 0: W1c, 1: W2c
        int nt = (task >> 2) & 7;
        int kt = task & 3;
        int col = nt * 16 + (lane & 15);
        int k0  = kt * 32 + (lane >> 4) * 8;
        unsigned short tmp[8];
        #pragma unroll
        for (int e = 0; e < 8; ++e) {
            int k = k0 + e;
            float v;
            if (m == 0) v = (k < 64) ? W1l[k * HID + col] : W1r[(k - 64) * HID + col];
            else        v = (col < 64) ? W2l[k * HID2 + col] : W2r[k * HID2 + (col - 64)];
            tmp[e] = f2bf(v);
        }
        unsigned short* dst = ((m == 0) ? Wf1 : Wf2)
                            + ((size_t)((nt * 4 + kt) * 64 + lane)) * 8;
        *(u16x8*)dst = *(const u16x8*)tmp;
    } else if (bid < 16 + CAST_BLOCKS) {
        int tid = (bid - 16) * 256 + threadIdx.x;      // one per 4 elements
        int node = tid >> 4;
        int q    = tid & 15;
        float4 v = ((const float4*)x)[tid];
        unsigned short o[4] = {f2bf(v.x), f2bf(v.y), f2bf(v.z), f2bf(v.w)};
        *(uint2*)(xbf + (size_t)node * 64 + q * 4) = *(const uint2*)o;
        int p = __builtin_amdgcn_cvt_pk_fp8_f32(v.x, v.y, 0, false);
        p     = __builtin_amdgcn_cvt_pk_fp8_f32(v.z, v.w, p, true);
        *(unsigned int*)(x8 + (size_t)node * 64 + q * 4) = (unsigned int)p;
    } else {
        for (int i = threadIdx.x; i < NB; i += 256) bucketTotal[i] = 0;
    }
}

// ---------------------------------------------------------------------------
// Binning pass 1: per-block bucket histogram (int4 edge reads).
// ---------------------------------------------------------------------------
__global__ __launch_bounds__(256) void bin_count(
    const int* __restrict__ dst,
    int* __restrict__ bucketTotal,     // [NB] (zeroed by prep_all)
    int* __restrict__ perBlockBase)    // [BIN_BLOCKS*NB]
{
    __shared__ int cnt[NB];
    const int t = threadIdx.x;
    for (int i = t; i < NB; i += 256) cnt[i] = 0;
    __syncthreads();
    const int e40 = blockIdx.x * (BIN_CHUNK / 4);
    const int4* dst4 = (const int4*)dst;
    #pragma unroll
    for (int i = 0; i < BIN_CHUNK / 4 / 256; ++i) {
        int ei = e40 + i * 256 + t;
        if (ei < N_EDGES / 4) {
            int4 d = dst4[ei];
            atomicAdd(&cnt[d.x >> 7], 1);
            atomicAdd(&cnt[d.y >> 7], 1);
            atomicAdd(&cnt[d.z >> 7], 1);
            atomicAdd(&cnt[d.w >> 7], 1);
        }
    }
    __syncthreads();
    for (int b = t; b < NB; b += 256) {
        int c = cnt[b];
        if (c) perBlockBase[blockIdx.x * NB + b] = atomicAdd(&bucketTotal[b], c);
    }
}

// ---------------------------------------------------------------------------
// Binning pass 2: exclusive scan of the 782 bucket totals (one block)
// ---------------------------------------------------------------------------
__global__ __launch_bounds__(1024) void bucket_scan(
    const int* __restrict__ bucketTotal, int* __restrict__ bucketStart)
{
    __shared__ int s[1024];
    const int t = threadIdx.x;
    int v = (t < NB) ? bucketTotal[t] : 0;
    s[t] = v;
    __syncthreads();
    #pragma unroll
    for (int off = 1; off < 1024; off <<= 1) {
        int u = (t >= off) ? s[t - off] : 0;
        __syncthreads();
        s[t] += u;
        __syncthreads();
    }
    if (t < NB) bucketStart[t] = s[t] - v;
    if (t == 0) bucketStart[NB] = N_EDGES;
}

// ---------------------------------------------------------------------------
// Binning pass 3: write packed (src<<7 | localDst) into bucket-grouped order
// ---------------------------------------------------------------------------
__global__ __launch_bounds__(256) void bin_write(
    const int* __restrict__ src, const int* __restrict__ dst,
    const int* __restrict__ bucketStart,
    const int* __restrict__ perBlockBase,
    unsigned int* __restrict__ binned)   // [E]
{
    __shared__ int cur[NB];
    const int t = threadIdx.x;
    for (int i = t; i < NB; i += 256) cur[i] = 0;
    __syncthreads();
    const int e40 = blockIdx.x * (BIN_CHUNK / 4);
    const int4* dst4 = (const int4*)dst;
    const int4* src4 = (const int4*)src;
    #pragma unroll
    for (int i = 0; i < BIN_CHUNK / 4 / 256; ++i) {
        int ei = e40 + i * 256 + t;
        if (ei < N_EDGES / 4) {
            int4 d = dst4[ei];
            int4 s = src4[ei];
            int ds[4] = {d.x, d.y, d.z, d.w};
            int ss[4] = {s.x, s.y, s.z, s.w};
            #pragma unroll
            for (int k = 0; k < 4; ++k) {
                int b = ds[k] >> 7;
                int pos = bucketStart[b] + perBlockBase[blockIdx.x * NB + b]
                        + atomicAdd(&cur[b], 1);
                binned[pos] = ((unsigned int)ss[k] << 7) | (unsigned int)(ds[k] & 127);
            }
        }
    }
}

// ---------------------------------------------------------------------------
// bucket_sort: one block per bucket. Stage packed edges in LDS, 128-bin
// histogram + scan -> rowStart, then local scatter -> sortedSrc.
// ---------------------------------------------------------------------------
__global__ __launch_bounds__(256) void bucket_sort(
    const unsigned int* __restrict__ binned,
    const int* __restrict__ bucketStart,
    int* __restrict__ sortedSrc,      // [E]
    int* __restrict__ rowStart)       // [N+1]
{
    __shared__ unsigned int stage[SORT_CAP];
    __shared__ int hist[NPB];
    __shared__ int cur[NPB];

    const int b  = blockIdx.x;
    const int t  = threadIdx.x;
    const int bs = bucketStart[b];
    const int be = bucketStart[b + 1];
    const int total = be - bs;

    if (t < NPB) hist[t] = 0;
    __syncthreads();

    if (total <= SORT_CAP) {
        for (int i = t; i < total; i += 256) {
            unsigned int p = binned[bs + i];
            stage[i] = p;
            atomicAdd(&hist[p & 127], 1);
        }
        __syncthreads();
        int orig = (t < NPB) ? hist[t] : 0;
        __syncthreads();
        #pragma unroll
        for (int off = 1; off < NPB; off <<= 1) {
            int v = (t < NPB && t >= off) ? hist[t - off] : 0;
            __syncthreads();
            if (t < NPB) hist[t] += v;
            __syncthreads();
        }
        if (t < NPB) {
            int excl = hist[t] - orig;
            int node = b * NPB + t;
            if (node < N_NODES) rowStart[node] = bs + excl;
            cur[t] = excl;
        }
        if (b == 0 && t == 0) rowStart[N_NODES] = N_EDGES;
        __syncthreads();
        for (int i = t; i < total; i += 256) {
            unsigned int p = stage[i];
            int pos = atomicAdd(&cur[p & 127], 1);
            sortedSrc[bs + pos] = (int)(p >> 7);
        }
    } else {
        for (int i = t; i < total; i += 256)
            atomicAdd(&hist[binned[bs + i] & 127], 1);
        __syncthreads();
        int orig = (t < NPB) ? hist[t] : 0;
        __syncthreads();
        #pragma unroll
        for (int off = 1; off < NPB; off <<= 1) {
            int v = (t < NPB && t >= off) ? hist[t - off] : 0;
            __syncthreads();
            if (t < NPB) hist[t] += v;
            __syncthreads();
        }
        if (t < NPB) {
            int excl = hist[t] - orig;
            int node = b * NPB + t;
            if (node < N_NODES) rowStart[node] = bs + excl;
            cur[t] = excl;
        }
        if (b == 0 && t == 0) rowStart[N_NODES] = N_EDGES;
        __syncthreads();
        for (int i = t; i < total; i += 256) {
            unsigned int p = binned[bs + i];
            int pos = atomicAdd(&cur[p & 127], 1);
            sortedSrc[bs + pos] = (int)(p >> 7);
        }
    }
}

// ---------------------------------------------------------------------------
// gemm_fused_g: gather1 fused into the GEMM stage-A (4 lanes/node, lane owns
// 16 features via one fp8 uint4 = 16 edges/load-instr). Mean -> LDS only.
// Then GEMM1 -> bn1/relu -> GEMM2 -> t1 fp8 / r1 bf16(+b2l).
// launch_bounds(256,8): 8 blocks/CU (LDS 17.4KB x8 = 139KB < 160KB; VGPR<=64)
// -> whole 1563-block grid co-resident, 2x latency hiding in gather phase.
// ---------------------------------------------------------------------------
__global__ __launch_bounds__(256, 8) void gemm_fused_g(
    const int* __restrict__ rowStart,
    const int* __restrict__ sortedSrc,
    const unsigned char* __restrict__ x8,      // [N,64] fp8
    const unsigned short* __restrict__ xbf,    // [N,64] bf16
    const unsigned short* __restrict__ Wf1,
    const unsigned short* __restrict__ Wf2,
    const float* __restrict__ b1l,
    const float* __restrict__ g1, const float* __restrict__ be1,
    const float* __restrict__ m1, const float* __restrict__ v1,
    const float* __restrict__ b2l,
    unsigned char* __restrict__ t1f8,          // [N,64] fp8 e4m3
    unsigned short* __restrict__ r1bf)         // [N,64] bf16 (h1@W2r + b2l)
{
    __shared__ unsigned short Al[64 * 136];    // row stride 272B (17x16B)

    const int t = threadIdx.x;
    const int w = t >> 6, l = t & 63;
    const int n0 = blockIdx.x * 64;
    const int r   = t >> 2;          // local node 0..63
    const int sub = t & 3;           // 16-feature block
    const int gb  = l & 60;          // 4-lane group base within wave
    const int node = n0 + r;

    // ---- stage x-half (bf16) into LDS cols [64,128) ----
    {
        unsigned short* drow = &Al[r * 136 + 64 + sub * 16];
        if (node < N_NODES) {
            const uint4* sp = (const uint4*)(xbf + (size_t)node * 64 + sub * 16);
            uint4 v0 = sp[0], v1 = sp[1];
            *(uint4*)drow = v0;
            *(uint4*)(drow + 8) = v1;
        } else {
            uint4 z; z.x = z.y = z.z = z.w = 0u;
            *(uint4*)drow = z;
            *(uint4*)(drow + 8) = z;
        }
    }

    // ---- gather mean from x8 -> LDS cols [0,64) ----
    {
        unsigned short* drow = &Al[r * 136 + sub * 16];
        if (node < N_NODES) {
            const int b = rowStart[node], e = rowStart[node + 1];
            float a[16] = {};
            for (int base = b; base < e; base += 4) {
                const int cnt = min(e - base, 4);            // group-uniform
                int srcv = (base + sub < e) ? sortedSrc[base + sub] : 0;
                if (cnt == 4) {
                    int s0 = __shfl(srcv, gb + 0);
                    int s1 = __shfl(srcv, gb + 1);
                    int s2 = __shfl(srcv, gb + 2);
                    int s3 = __shfl(srcv, gb + 3);
                    uint4 v0 = *(const uint4*)(x8 + (size_t)s0 * 64 + sub * 16);
                    uint4 v1 = *(const uint4*)(x8 + (size_t)s1 * 64 + sub * 16);
                    uint4 v2 = *(const uint4*)(x8 + (size_t)s2 * 64 + sub * 16);
                    uint4 v3 = *(const uint4*)(x8 + (size_t)s3 * 64 + sub * 16);
                    accum_fp8x16(a, v0);
                    accum_fp8x16(a, v1);
                    accum_fp8x16(a, v2);
                    accum_fp8x16(a, v3);
                } else {
                    for (int i = 0; i < cnt; ++i) {
                        int s0 = __shfl(srcv, gb + i);
                        uint4 v0 = *(const uint4*)(x8 + (size_t)s0 * 64 + sub * 16);
                        accum_fp8x16(a, v0);
                    }
                }
            }
            float inv = 1.0f / fmaxf((float)(e - b), 1.0f);
            unsigned short o[16];
            #pragma unroll
            for (int i = 0; i < 16; ++i) o[i] = f2bf(a[i] * inv);
            *(uint4*)drow       = *(const uint4*)o;
            *(uint4*)(drow + 8) = *(const uint4*)(o + 8);
        } else {
            uint4 z; z.x = z.y = z.z = z.w = 0u;
            *(uint4*)drow = z;
            *(uint4*)(drow + 8) = z;
        }
    }
    __syncthreads();

    const int row = l & 15, kq = l >> 4;

    // ---- GEMM1 ----
    f32x4 acc[4][2];
    #pragma unroll
    for (int a = 0; a < 4; ++a)
        #pragma unroll
        for (int b = 0; b < 2; ++b) acc[a][b] = (f32x4)(0.0f);

    #pragma unroll
    for (int kt = 0; kt < 4; ++kt) {
        bf16x8 bfr[2];
        #pragma unroll
        for (int n = 0; n < 2; ++n)
            bfr[n] = __builtin_bit_cast(bf16x8,
                *(const u16x8*)(Wf1 + ((size_t)(((2 * w + n) * 4 + kt) * 64 + l)) * 8));
        #pragma unroll
        for (int mt = 0; mt < 4; ++mt) {
            bf16x8 afr = __builtin_bit_cast(bf16x8,
                *(const u16x8*)&Al[(mt * 16 + row) * 136 + kt * 32 + kq * 8]);
            #pragma unroll
            for (int n = 0; n < 2; ++n)
                acc[mt][n] = __builtin_amdgcn_mfma_f32_16x16x32_bf16(
                    afr, bfr[n], acc[mt][n], 0, 0, 0);
        }
    }
    __syncthreads();   // all reads of A done before h1 overwrites

    // ---- epilogue 1: h1 = relu(bn1(pre)) -> Al (bf16) ----
    #pragma unroll
    for (int n = 0; n < 2; ++n) {
        int j = w * 32 + n * 16 + (l & 15);
        float s  = g1[j] * rsqrtf(v1[j] + BN_EPS);
        float of = be1[j] + (b1l[j] - m1[j]) * s;
        #pragma unroll
        for (int mt = 0; mt < 4; ++mt) {
            #pragma unroll
            for (int i = 0; i < 4; ++i) {
                float h = fmaxf(fmaf(acc[mt][n][i], s, of), 0.0f);
                Al[(mt * 16 + kq * 4 + i) * 136 + j] = f2bf(h);
            }
        }
    }
    __syncthreads();

    // ---- GEMM2 ----
    f32x4 acc2[4][2];
    #pragma unroll
    for (int a = 0; a < 4; ++a)
        #pragma unroll
        for (int b = 0; b < 2; ++b) acc2[a][b] = (f32x4)(0.0f);

    #pragma unroll
    for (int kt = 0; kt < 4; ++kt) {
        bf16x8 bfr[2];
        #pragma unroll
        for (int n = 0; n < 2; ++n)
            bfr[n] = __builtin_bit_cast(bf16x8,
                *(const u16x8*)(Wf2 + ((size_t)(((2 * w + n) * 4 + kt) * 64 + l)) * 8));
        #pragma unroll
        for (int mt = 0; mt < 4; ++mt) {
            bf16x8 afr = __builtin_bit_cast(bf16x8,
                *(const u16x8*)&Al[(mt * 16 + row) * 136 + kt * 32 + kq * 8]);
            #pragma unroll
            for (int n = 0; n < 2; ++n)
                acc2[mt][n] = __builtin_amdgcn_mfma_f32_16x16x32_bf16(
                    afr, bfr[n], acc2[mt][n], 0, 0, 0);
        }
    }

    // ---- epilogue 2: cols [0,64) -> t1 fp8 ; [64,128) -> r1 bf16 (+b2l) ----
    #pragma unroll
    for (int n = 0; n < 2; ++n) {
        int j = w * 32 + n * 16 + (l & 15);
        float bl = (w >= 2) ? b2l[j - 64] : 0.0f;
        #pragma unroll
        for (int mt = 0; mt < 4; ++mt) {
            #pragma unroll
            for (int i = 0; i < 4; ++i) {
                int nn = n0 + mt * 16 + kq * 4 + i;
                if (nn < N_NODES) {
                    float vv = acc2[mt][n][i];
                    if (w < 2) {
                        int p = __builtin_amdgcn_cvt_pk_fp8_f32(vv, vv, 0, false);
                        t1f8[(size_t)nn * 64 + j] = (unsigned char)(p & 0xff);
                    } else {
                        r1bf[(size_t)nn * 64 + (j - 64)] = f2bf(vv + bl);
                    }
                }
            }
        }
    }
}

// ---------------------------------------------------------------------------
// gather2_e: eighth-wave gather of fp8 t1 rows, 8-deep load batch in the
// full-chunk path, + fused BN2/ReLU/classifier epilogue.
// ---------------------------------------------------------------------------
__global__ __launch_bounds__(256) void gather2_e(
    const unsigned char* __restrict__ t1f8,  // [N,64] fp8 e4m3
    const int* __restrict__ rowStart,
    const int* __restrict__ sortedSrc,
    const unsigned short* __restrict__ r1bf, // [N,64] bf16
    const float* __restrict__ g2, const float* __restrict__ be2,
    const float* __restrict__ m2, const float* __restrict__ v2,
    const float* __restrict__ Wc, const float* __restrict__ bc,
    float* __restrict__ out)                 // [N,2]
{
    const int node = (int)((blockIdx.x * 256u + threadIdx.x) >> 3);
    const int lane = threadIdx.x & 63;
    const int f    = lane & 7;
    const int nb   = lane & 56;
    const int b = rowStart[node], e = rowStart[node + 1];

    float a0[8] = {}, a1[8] = {}, a2[8] = {}, a3[8] = {};

    for (int base = b; base < e; base += 8) {
        const int cnt = min(e - base, 8);                   // group-uniform
        int srcv = (base + f < e) ? sortedSrc[base + f] : 0;
        if (cnt == 8) {
            int s0 = __shfl(srcv, nb + 0);
            int s1 = __shfl(srcv, nb + 1);
            int s2 = __shfl(srcv, nb + 2);
            int s3 = __shfl(srcv, nb + 3);
            int s4 = __shfl(srcv, nb + 4);
            int s5 = __shfl(srcv, nb + 5);
            int s6 = __shfl(srcv, nb + 6);
            int s7 = __shfl(srcv, nb + 7);
            uint2 v0 = *(const uint2*)(t1f8 + (size_t)s0 * 64 + f * 8);
            uint2 v1 = *(const uint2*)(t1f8 + (size_t)s1 * 64 + f * 8);
            uint2 v2 = *(const uint2*)(t1f8 + (size_t)s2 * 64 + f * 8);
            uint2 v3 = *(const uint2*)(t1f8 + (size_t)s3 * 64 + f * 8);
            uint2 v4 = *(const uint2*)(t1f8 + (size_t)s4 * 64 + f * 8);
            uint2 v5 = *(const uint2*)(t1f8 + (size_t)s5 * 64 + f * 8);
            uint2 v6 = *(const uint2*)(t1f8 + (size_t)s6 * 64 + f * 8);
            uint2 v7 = *(const uint2*)(t1f8 + (size_t)s7 * 64 + f * 8);
            accum_fp8x8(a0, v0);
            accum_fp8x8(a1, v1);
            accum_fp8x8(a2, v2);
            accum_fp8x8(a3, v3);
            accum_fp8x8(a0, v4);
            accum_fp8x8(a1, v5);
            accum_fp8x8(a2, v6);
            accum_fp8x8(a3, v7);
        } else {
            for (int i = 0; i < cnt; ++i) {
                int s0 = __shfl(srcv, nb + i);
                accum_fp8x8(a0, *(const uint2*)(t1f8 + (size_t)s0 * 64 + f * 8));
            }
        }
    }
    #pragma unroll
    for (int i = 0; i < 8; ++i) a0[i] = (a0[i] + a1[i]) + (a2[i] + a3[i]);

    // ---- epilogue: features fe = f*8 + i ----
    const float inv = 1.0f / fmaxf((float)(e - b), 1.0f);
    const int f0 = f * 8;
    uint4 rv = *(const uint4*)(r1bf + (size_t)node * 64 + f0);
    unsigned int rw[4] = {rv.x, rv.y, rv.z, rv.w};
    float l0 = 0.f, l1 = 0.f;
    #pragma unroll
    for (int i = 0; i < 8; ++i) {
        int fe = f0 + i;
        unsigned int wv = rw[i >> 1];
        float rr = (i & 1) ? __builtin_bit_cast(float, wv)          // hi bf16, unmasked
                           : __builtin_bit_cast(float, wv << 16);
        float pre = a0[i] * inv + rr;             // b2l folded into r1
        float s   = g2[fe] * rsqrtf(v2[fe] + BN_EPS);
        float h2  = fmaxf((pre - m2[fe]) * s + be2[fe], 0.0f);
        l0 = fmaf(h2, Wc[fe * 2 + 0], l0);
        l1 = fmaf(h2, Wc[fe * 2 + 1], l1);
    }
    #pragma unroll
    for (int off = 4; off > 0; off >>= 1) {
        l0 += __shfl_xor(l0, off);
        l1 += __shfl_xor(l1, off);
    }
    if (f == 0) {
        out[(size_t)node * 2 + 0] = l0 + bc[0];
        out[(size_t)node * 2 + 1] = l1 + bc[1];
    }
}

// ---------------------------------------------------------------------------
extern "C" void kernel_launch(void* const* d_in, const int* in_sizes, int n_in,
                              void* d_out, int out_size, void* d_ws, size_t ws_size,
                              hipStream_t stream)
{
    const float* x    = (const float*)d_in[0];
    const int*   eidx = (const int*)d_in[1];   // [2, E]: row 0 = src, row 1 = dst
    const float* W1l  = (const float*)d_in[2];
    const float* b1l  = (const float*)d_in[3];
    const float* W1r  = (const float*)d_in[4];
    const float* W2l  = (const float*)d_in[5];
    const float* b2l  = (const float*)d_in[6];
    const float* W2r  = (const float*)d_in[7];
    const float* g1   = (const float*)d_in[8];
    const float* be1  = (const float*)d_in[9];
    const float* m1   = (const float*)d_in[10];
    const float* v1   = (const float*)d_in[11];
    const float* g2   = (const float*)d_in[12];
    const float* be2  = (const float*)d_in[13];
    const float* m2   = (const float*)d_in[14];
    const float* v2   = (const float*)d_in[15];
    const float* Wc   = (const float*)d_in[16];
    const float* bc   = (const float*)d_in[17];
    float* out = (float*)d_out;

    const int* src = eidx;
    const int* dst = eidx + N_EDGES;

    // ---- workspace layout ----
    char* ws = (char*)d_ws;
    size_t off = 0;
    auto alloc = [&](size_t bytes) { void* p = ws + off; off = (off + bytes + 255) & ~(size_t)255; return p; };
    int* bucketTotal  = (int*)alloc((size_t)NB * 4);
    int* bucketStart  = (int*)alloc((size_t)(NB + 1) * 4);
    int* perBlockBase = (int*)alloc((size_t)BIN_BLOCKS * NB * 4);
    unsigned int* binned = (unsigned int*)alloc((size_t)N_EDGES * 4);
    int* sortedSrc    = (int*)alloc((size_t)N_EDGES * 4);
    int* rowStart     = (int*)alloc((size_t)(N_NODES + 1) * 4);
    unsigned short* Wf1  = (unsigned short*)alloc(128 * 128 * 2);
    unsigned short* Wf2  = (unsigned short*)alloc(128 * 128 * 2);
    unsigned short* xbf  = (unsigned short*)alloc((size_t)N_NODES * 64 * 2);
    unsigned char*  x8   = (unsigned char*)alloc((size_t)N_NODES * 64);
    unsigned char*  t1f8 = (unsigned char*)alloc((size_t)N_NODES * 64);
    unsigned short* r1bf = (unsigned short*)alloc((size_t)N_NODES * 64 * 2);

    const int gemmGrid    = (N_NODES + 63) / 64;             // 1563
    const int gatherGrid  = (N_NODES * 8) / 256;             // 3125 (8 lanes/node)

    // ---- prep (wfrag + cast + zero bucketTotal in one kernel) ----
    prep_all<<<16 + CAST_BLOCKS + 1, 256, 0, stream>>>(
        x, W1l, W1r, W2l, W2r, Wf1, Wf2, xbf, x8, bucketTotal);

    // ---- counting sort of edges by dst ----
    bin_count  <<<BIN_BLOCKS, 256, 0, stream>>>(dst, bucketTotal, perBlockBase);
    bucket_scan<<<1, 1024, 0, stream>>>(bucketTotal, bucketStart);
    bin_write  <<<BIN_BLOCKS, 256, 0, stream>>>(src, dst, bucketStart, perBlockBase, binned);
    bucket_sort<<<NB, 256, 0, stream>>>(binned, bucketStart, sortedSrc, rowStart);

    // ---- fused: gather1 (in-LDS mean) + GEMM1 + bn1/relu + GEMM2 ----
    gemm_fused_g<<<gemmGrid, 256, 0, stream>>>(
        rowStart, sortedSrc, x8, xbf, Wf1, Wf2,
        b1l, g1, be1, m1, v1, b2l, t1f8, r1bf);

    // ---- layer 2: gather fp8 t1 + fused BN2/ReLU/classifier -> out ----
    gather2_e<<<gatherGrid, 256, 0, stream>>>(
        t1f8, rowStart, sortedSrc, r1bf, g2, be2, m2, v2, Wc, bc, out);
}

// Round 20
// 136.534 us; speedup vs baseline: 1.4161x; 1.4161x over previous
//
#include <hip/hip_runtime.h>
#include <math.h>

#define N_NODES 100000
#define IN_DIM 64
#define HID 128
#define HID2 64
#define N_EDGES 1600000
#define BN_EPS 1e-5f

// bucketing: 128 dst nodes per bucket
#define NPB 128
#define NB 782            // ceil(100000/128)
#define BIN_BLOCKS 391
#define BIN_CHUNK 4096    // 391*4096 >= 1.6M
#define SORT_CAP 4096     // bucket capacity for LDS sort (mean 2048, sigma ~45)
#define CAST_BLOCKS 6250  // N_NODES*16/256

typedef __attribute__((ext_vector_type(8))) __bf16 bf16x8;
typedef __attribute__((ext_vector_type(4))) float f32x4;
typedef __attribute__((ext_vector_type(2))) float f32x2;
typedef __attribute__((ext_vector_type(8))) unsigned short u16x8;

__device__ __forceinline__ unsigned short f2bf(float f) {
    unsigned int u = __builtin_bit_cast(unsigned int, f);
    u += 0x7fffu + ((u >> 16) & 1u);          // round-to-nearest-even
    return (unsigned short)(u >> 16);
}

// accumulate 8 fp8 e4m3 (one uint2) into 8 fp32 via HW converter
__device__ __forceinline__ void accum_fp8x8(float a[8], uint2 v) {
    f32x2 p0 = __builtin_amdgcn_cvt_pk_f32_fp8((int)v.x, false);
    f32x2 p1 = __builtin_amdgcn_cvt_pk_f32_fp8((int)v.x, true);
    f32x2 p2 = __builtin_amdgcn_cvt_pk_f32_fp8((int)v.y, false);
    f32x2 p3 = __builtin_amdgcn_cvt_pk_f32_fp8((int)v.y, true);
    a[0] += p0.x; a[1] += p0.y; a[2] += p1.x; a[3] += p1.y;
    a[4] += p2.x; a[5] += p2.y; a[6] += p3.x; a[7] += p3.y;
}

// accumulate 16 fp8 e4m3 (one uint4) into 16 fp32
__device__ __forceinline__ void accum_fp8x16(float a[16], uint4 v) {
    unsigned int w[4] = {v.x, v.y, v.z, v.w};
    #pragma unroll
    for (int k = 0; k < 4; ++k) {
        f32x2 lo = __builtin_amdgcn_cvt_pk_f32_fp8((int)w[k], false);
        f32x2 hi = __builtin_amdgcn_cvt_pk_f32_fp8((int)w[k], true);
        a[4*k+0] += lo.x; a[4*k+1] += lo.y;
        a[4*k+2] += hi.x; a[4*k+3] += hi.y;
    }
}

// ---------------------------------------------------------------------------
// prep_all: one kernel for all prep work.
//   blocks [0,16):              pack W1c/W2c into bf16 MFMA B-fragment order
//   blocks [16,16+CAST_BLOCKS): cast x -> bf16 (xbf) AND fp8 (x8 table)
//   last block:                 zero bucketTotal
// ---------------------------------------------------------------------------
__global__ __launch_bounds__(256) void prep_all(
    const float* __restrict__ x,
    const float* __restrict__ W1l, const float* __restrict__ W1r,
    const float* __restrict__ W2l, const float* __restrict__ W2r,
    unsigned short* __restrict__ Wf1, unsigned short* __restrict__ Wf2,
    unsigned short* __restrict__ xbf,    // [N,64] bf16
    unsigned char* __restrict__ x8,      // [N,64] fp8
    int* __restrict__ bucketTotal)
{
    const int bid = blockIdx.x;
    if (bid < 16) {
        int task = bid * 4 + (threadIdx.x >> 6);   // 0..63
        int lane = threadIdx.x & 63;
        int m  = task >> 5;          // 0: W1c, 1: W2c
        int nt = (task >> 2) & 7;
        int kt = task & 3;
        int col = nt * 16 + (lane & 15);
        int k0  = kt * 32 + (lane >> 4) * 8;
        unsigned short tmp[8];
        #pragma unroll
        for (int e = 0; e < 8; ++e) {
            int k = k0 + e;
            float v;
            if (m == 0) v = (k < 64) ? W1l[k * HID + col] : W1r[(k - 64) * HID + col];
            else        v = (col < 64) ? W2l[k * HID2 + col] : W2r[k * HID2 + (col - 64)];
            tmp[e] = f2bf(v);
        }
        unsigned short* dst = ((m == 0) ? Wf1 : Wf2)
                            + ((size_t)((nt * 4 + kt) * 64 + lane)) * 8;
        *(u16x8*)dst = *(const u16x8*)tmp;
    } else if (bid < 16 + CAST_BLOCKS) {
        int tid = (bid - 16) * 256 + threadIdx.x;      // one per 4 elements
        int node = tid >> 4;
        int q    = tid & 15;
        float4 v = ((const float4*)x)[tid];
        unsigned short o[4] = {f2bf(v.x), f2bf(v.y), f2bf(v.z), f2bf(v.w)};
        *(uint2*)(xbf + (size_t)node * 64 + q * 4) = *(const uint2*)o;
        int p = __builtin_amdgcn_cvt_pk_fp8_f32(v.x, v.y, 0, false);
        p     = __builtin_amdgcn_cvt_pk_fp8_f32(v.z, v.w, p, true);
        *(unsigned int*)(x8 + (size_t)node * 64 + q * 4) = (unsigned int)p;
    } else {
        for (int i = threadIdx.x; i < NB; i += 256) bucketTotal[i] = 0;
    }
}

// ---------------------------------------------------------------------------
// Binning pass 1: per-block bucket histogram (int4 edge reads).
// ---------------------------------------------------------------------------
__global__ __launch_bounds__(256) void bin_count(
    const int* __restrict__ dst,
    int* __restrict__ bucketTotal,     // [NB] (zeroed by prep_all)
    int* __restrict__ perBlockBase)    // [BIN_BLOCKS*NB]
{
    __shared__ int cnt[NB];
    const int t = threadIdx.x;
    for (int i = t; i < NB; i += 256) cnt[i] = 0;
    __syncthreads();
    const int e40 = blockIdx.x * (BIN_CHUNK / 4);
    const int4* dst4 = (const int4*)dst;
    #pragma unroll
    for (int i = 0; i < BIN_CHUNK / 4 / 256; ++i) {
        int ei = e40 + i * 256 + t;
        if (ei < N_EDGES / 4) {
            int4 d = dst4[ei];
            atomicAdd(&cnt[d.x >> 7], 1);
            atomicAdd(&cnt[d.y >> 7], 1);
            atomicAdd(&cnt[d.z >> 7], 1);
            atomicAdd(&cnt[d.w >> 7], 1);
        }
    }
    __syncthreads();
    for (int b = t; b < NB; b += 256) {
        int c = cnt[b];
        if (c) perBlockBase[blockIdx.x * NB + b] = atomicAdd(&bucketTotal[b], c);
    }
}

// ---------------------------------------------------------------------------
// Binning pass 2: exclusive scan of the 782 bucket totals (one block)
// ---------------------------------------------------------------------------
__global__ __launch_bounds__(1024) void bucket_scan(
    const int* __restrict__ bucketTotal, int* __restrict__ bucketStart)
{
    __shared__ int s[1024];
    const int t = threadIdx.x;
    int v = (t < NB) ? bucketTotal[t] : 0;
    s[t] = v;
    __syncthreads();
    #pragma unroll
    for (int off = 1; off < 1024; off <<= 1) {
        int u = (t >= off) ? s[t - off] : 0;
        __syncthreads();
        s[t] += u;
        __syncthreads();
    }
    if (t < NB) bucketStart[t] = s[t] - v;
    if (t == 0) bucketStart[NB] = N_EDGES;
}

// ---------------------------------------------------------------------------
// Binning pass 3: write packed (src<<7 | localDst) into bucket-grouped order
// ---------------------------------------------------------------------------
__global__ __launch_bounds__(256) void bin_write(
    const int* __restrict__ src, const int* __restrict__ dst,
    const int* __restrict__ bucketStart,
    const int* __restrict__ perBlockBase,
    unsigned int* __restrict__ binned)   // [E]
{
    __shared__ int cur[NB];
    const int t = threadIdx.x;
    for (int i = t; i < NB; i += 256) cur[i] = 0;
    __syncthreads();
    const int e40 = blockIdx.x * (BIN_CHUNK / 4);
    const int4* dst4 = (const int4*)dst;
    const int4* src4 = (const int4*)src;
    #pragma unroll
    for (int i = 0; i < BIN_CHUNK / 4 / 256; ++i) {
        int ei = e40 + i * 256 + t;
        if (ei < N_EDGES / 4) {
            int4 d = dst4[ei];
            int4 s = src4[ei];
            int ds[4] = {d.x, d.y, d.z, d.w};
            int ss[4] = {s.x, s.y, s.z, s.w};
            #pragma unroll
            for (int k = 0; k < 4; ++k) {
                int b = ds[k] >> 7;
                int pos = bucketStart[b] + perBlockBase[blockIdx.x * NB + b]
                        + atomicAdd(&cur[b], 1);
                binned[pos] = ((unsigned int)ss[k] << 7) | (unsigned int)(ds[k] & 127);
            }
        }
    }
}

// ---------------------------------------------------------------------------
// bucket_sort: one block per bucket. Stage packed edges in LDS, 128-bin
// histogram + scan -> rowStart, then local scatter -> sortedSrc.
// ---------------------------------------------------------------------------
__global__ __launch_bounds__(256) void bucket_sort(
    const unsigned int* __restrict__ binned,
    const int* __restrict__ bucketStart,
    int* __restrict__ sortedSrc,      // [E]
    int* __restrict__ rowStart)       // [N+1]
{
    __shared__ unsigned int stage[SORT_CAP];
    __shared__ int hist[NPB];
    __shared__ int cur[NPB];

    const int b  = blockIdx.x;
    const int t  = threadIdx.x;
    const int bs = bucketStart[b];
    const int be = bucketStart[b + 1];
    const int total = be - bs;

    if (t < NPB) hist[t] = 0;
    __syncthreads();

    if (total <= SORT_CAP) {
        for (int i = t; i < total; i += 256) {
            unsigned int p = binned[bs + i];
            stage[i] = p;
            atomicAdd(&hist[p & 127], 1);
        }
        __syncthreads();
        int orig = (t < NPB) ? hist[t] : 0;
        __syncthreads();
        #pragma unroll
        for (int off = 1; off < NPB; off <<= 1) {
            int v = (t < NPB && t >= off) ? hist[t - off] : 0;
            __syncthreads();
            if (t < NPB) hist[t] += v;
            __syncthreads();
        }
        if (t < NPB) {
            int excl = hist[t] - orig;
            int node = b * NPB + t;
            if (node < N_NODES) rowStart[node] = bs + excl;
            cur[t] = excl;
        }
        if (b == 0 && t == 0) rowStart[N_NODES] = N_EDGES;
        __syncthreads();
        for (int i = t; i < total; i += 256) {
            unsigned int p = stage[i];
            int pos = atomicAdd(&cur[p & 127], 1);
            sortedSrc[bs + pos] = (int)(p >> 7);
        }
    } else {
        for (int i = t; i < total; i += 256)
            atomicAdd(&hist[binned[bs + i] & 127], 1);
        __syncthreads();
        int orig = (t < NPB) ? hist[t] : 0;
        __syncthreads();
        #pragma unroll
        for (int off = 1; off < NPB; off <<= 1) {
            int v = (t < NPB && t >= off) ? hist[t - off] : 0;
            __syncthreads();
            if (t < NPB) hist[t] += v;
            __syncthreads();
        }
        if (t < NPB) {
            int excl = hist[t] - orig;
            int node = b * NPB + t;
            if (node < N_NODES) rowStart[node] = bs + excl;
            cur[t] = excl;
        }
        if (b == 0 && t == 0) rowStart[N_NODES] = N_EDGES;
        __syncthreads();
        for (int i = t; i < total; i += 256) {
            unsigned int p = binned[bs + i];
            int pos = atomicAdd(&cur[p & 127], 1);
            sortedSrc[bs + pos] = (int)(p >> 7);
        }
    }
}

// ---------------------------------------------------------------------------
// gemm_fused_g: gather1 fused into the GEMM stage-A (4 lanes/node, lane owns
// 16 features via one fp8 uint4 = 16 edges/load-instr). Mean -> LDS only.
// sortedSrc index load for chunk k+1 is PREFETCHED during chunk k (hides
// ~200cy L2 latency under the random row loads). launch_bounds(256,4):
// 56 VGPR, no spills (the (256,8) experiment spilled: 32 VGPR, 3x FETCH).
// ---------------------------------------------------------------------------
__global__ __launch_bounds__(256, 4) void gemm_fused_g(
    const int* __restrict__ rowStart,
    const int* __restrict__ sortedSrc,
    const unsigned char* __restrict__ x8,      // [N,64] fp8
    const unsigned short* __restrict__ xbf,    // [N,64] bf16
    const unsigned short* __restrict__ Wf1,
    const unsigned short* __restrict__ Wf2,
    const float* __restrict__ b1l,
    const float* __restrict__ g1, const float* __restrict__ be1,
    const float* __restrict__ m1, const float* __restrict__ v1,
    const float* __restrict__ b2l,
    unsigned char* __restrict__ t1f8,          // [N,64] fp8 e4m3
    unsigned short* __restrict__ r1bf)         // [N,64] bf16 (h1@W2r + b2l)
{
    __shared__ unsigned short Al[64 * 136];    // row stride 272B (17x16B)

    const int t = threadIdx.x;
    const int w = t >> 6, l = t & 63;
    const int n0 = blockIdx.x * 64;
    const int r   = t >> 2;          // local node 0..63
    const int sub = t & 3;           // 16-feature block
    const int gb  = l & 60;          // 4-lane group base within wave
    const int node = n0 + r;

    // ---- stage x-half (bf16) into LDS cols [64,128) ----
    {
        unsigned short* drow = &Al[r * 136 + 64 + sub * 16];
        if (node < N_NODES) {
            const uint4* sp = (const uint4*)(xbf + (size_t)node * 64 + sub * 16);
            uint4 v0 = sp[0], v1 = sp[1];
            *(uint4*)drow = v0;
            *(uint4*)(drow + 8) = v1;
        } else {
            uint4 z; z.x = z.y = z.z = z.w = 0u;
            *(uint4*)drow = z;
            *(uint4*)(drow + 8) = z;
        }
    }

    // ---- gather mean from x8 -> LDS cols [0,64) (srcv prefetch pipeline) ----
    {
        unsigned short* drow = &Al[r * 136 + sub * 16];
        if (node < N_NODES) {
            const int b = rowStart[node], e = rowStart[node + 1];
            float a[16] = {};
            int srcv = (b + sub < e) ? sortedSrc[b + sub] : 0;
            for (int base = b; base < e; base += 4) {
                const int nb2 = base + 4;
                int nsrcv = (nb2 + sub < e) ? sortedSrc[nb2 + sub] : 0;  // prefetch
                const int cnt = min(e - base, 4);            // group-uniform
                if (cnt == 4) {
                    int s0 = __shfl(srcv, gb + 0);
                    int s1 = __shfl(srcv, gb + 1);
                    int s2 = __shfl(srcv, gb + 2);
                    int s3 = __shfl(srcv, gb + 3);
                    uint4 v0 = *(const uint4*)(x8 + (size_t)s0 * 64 + sub * 16);
                    uint4 v1 = *(const uint4*)(x8 + (size_t)s1 * 64 + sub * 16);
                    uint4 v2 = *(const uint4*)(x8 + (size_t)s2 * 64 + sub * 16);
                    uint4 v3 = *(const uint4*)(x8 + (size_t)s3 * 64 + sub * 16);
                    accum_fp8x16(a, v0);
                    accum_fp8x16(a, v1);
                    accum_fp8x16(a, v2);
                    accum_fp8x16(a, v3);
                } else {
                    for (int i = 0; i < cnt; ++i) {
                        int s0 = __shfl(srcv, gb + i);
                        uint4 v0 = *(const uint4*)(x8 + (size_t)s0 * 64 + sub * 16);
                        accum_fp8x16(a, v0);
                    }
                }
                srcv = nsrcv;
            }
            float inv = 1.0f / fmaxf((float)(e - b), 1.0f);
            unsigned short o[16];
            #pragma unroll
            for (int i = 0; i < 16; ++i) o[i] = f2bf(a[i] * inv);
            *(uint4*)drow       = *(const uint4*)o;
            *(uint4*)(drow + 8) = *(const uint4*)(o + 8);
        } else {
            uint4 z; z.x = z.y = z.z = z.w = 0u;
            *(uint4*)drow = z;
            *(uint4*)(drow + 8) = z;
        }
    }
    __syncthreads();

    const int row = l & 15, kq = l >> 4;

    // ---- GEMM1 ----
    f32x4 acc[4][2];
    #pragma unroll
    for (int a = 0; a < 4; ++a)
        #pragma unroll
        for (int b = 0; b < 2; ++b) acc[a][b] = (f32x4)(0.0f);

    #pragma unroll
    for (int kt = 0; kt < 4; ++kt) {
        bf16x8 bfr[2];
        #pragma unroll
        for (int n = 0; n < 2; ++n)
            bfr[n] = __builtin_bit_cast(bf16x8,
                *(const u16x8*)(Wf1 + ((size_t)(((2 * w + n) * 4 + kt) * 64 + l)) * 8));
        #pragma unroll
        for (int mt = 0; mt < 4; ++mt) {
            bf16x8 afr = __builtin_bit_cast(bf16x8,
                *(const u16x8*)&Al[(mt * 16 + row) * 136 + kt * 32 + kq * 8]);
            #pragma unroll
            for (int n = 0; n < 2; ++n)
                acc[mt][n] = __builtin_amdgcn_mfma_f32_16x16x32_bf16(
                    afr, bfr[n], acc[mt][n], 0, 0, 0);
        }
    }
    __syncthreads();   // all reads of A done before h1 overwrites

    // ---- epilogue 1: h1 = relu(bn1(pre)) -> Al (bf16) ----
    #pragma unroll
    for (int n = 0; n < 2; ++n) {
        int j = w * 32 + n * 16 + (l & 15);
        float s  = g1[j] * rsqrtf(v1[j] + BN_EPS);
        float of = be1[j] + (b1l[j] - m1[j]) * s;
        #pragma unroll
        for (int mt = 0; mt < 4; ++mt) {
            #pragma unroll
            for (int i = 0; i < 4; ++i) {
                float h = fmaxf(fmaf(acc[mt][n][i], s, of), 0.0f);
                Al[(mt * 16 + kq * 4 + i) * 136 + j] = f2bf(h);
            }
        }
    }
    __syncthreads();

    // ---- GEMM2 ----
    f32x4 acc2[4][2];
    #pragma unroll
    for (int a = 0; a < 4; ++a)
        #pragma unroll
        for (int b = 0; b < 2; ++b) acc2[a][b] = (f32x4)(0.0f);

    #pragma unroll
    for (int kt = 0; kt < 4; ++kt) {
        bf16x8 bfr[2];
        #pragma unroll
        for (int n = 0; n < 2; ++n)
            bfr[n] = __builtin_bit_cast(bf16x8,
                *(const u16x8*)(Wf2 + ((size_t)(((2 * w + n) * 4 + kt) * 64 + l)) * 8));
        #pragma unroll
        for (int mt = 0; mt < 4; ++mt) {
            bf16x8 afr = __builtin_bit_cast(bf16x8,
                *(const u16x8*)&Al[(mt * 16 + row) * 136 + kt * 32 + kq * 8]);
            #pragma unroll
            for (int n = 0; n < 2; ++n)
                acc2[mt][n] = __builtin_amdgcn_mfma_f32_16x16x32_bf16(
                    afr, bfr[n], acc2[mt][n], 0, 0, 0);
        }
    }

    // ---- epilogue 2: cols [0,64) -> t1 fp8 ; [64,128) -> r1 bf16 (+b2l) ----
    #pragma unroll
    for (int n = 0; n < 2; ++n) {
        int j = w * 32 + n * 16 + (l & 15);
        float bl = (w >= 2) ? b2l[j - 64] : 0.0f;
        #pragma unroll
        for (int mt = 0; mt < 4; ++mt) {
            #pragma unroll
            for (int i = 0; i < 4; ++i) {
                int nn = n0 + mt * 16 + kq * 4 + i;
                if (nn < N_NODES) {
                    float vv = acc2[mt][n][i];
                    if (w < 2) {
                        int p = __builtin_amdgcn_cvt_pk_fp8_f32(vv, vv, 0, false);
                        t1f8[(size_t)nn * 64 + j] = (unsigned char)(p & 0xff);
                    } else {
                        r1bf[(size_t)nn * 64 + (j - 64)] = f2bf(vv + bl);
                    }
                }
            }
        }
    }
}

// ---------------------------------------------------------------------------
// gather2_e: eighth-wave gather of fp8 t1 rows, 8-deep load batch + srcv
// prefetch pipeline, + fused BN2/ReLU/classifier epilogue.
// ---------------------------------------------------------------------------
__global__ __launch_bounds__(256) void gather2_e(
    const unsigned char* __restrict__ t1f8,  // [N,64] fp8 e4m3
    const int* __restrict__ rowStart,
    const int* __restrict__ sortedSrc,
    const unsigned short* __restrict__ r1bf, // [N,64] bf16
    const float* __restrict__ g2, const float* __restrict__ be2,
    const float* __restrict__ m2, const float* __restrict__ v2,
    const float* __restrict__ Wc, const float* __restrict__ bc,
    float* __restrict__ out)                 // [N,2]
{
    const int node = (int)((blockIdx.x * 256u + threadIdx.x) >> 3);
    const int lane = threadIdx.x & 63;
    const int f    = lane & 7;
    const int nb   = lane & 56;
    const int b = rowStart[node], e = rowStart[node + 1];

    float a0[8] = {}, a1[8] = {}, a2[8] = {}, a3[8] = {};

    int srcv = (b + f < e) ? sortedSrc[b + f] : 0;
    for (int base = b; base < e; base += 8) {
        const int nb2 = base + 8;
        int nsrcv = (nb2 + f < e) ? sortedSrc[nb2 + f] : 0;   // prefetch
        const int cnt = min(e - base, 8);                     // group-uniform
        if (cnt == 8) {
            int s0 = __shfl(srcv, nb + 0);
            int s1 = __shfl(srcv, nb + 1);
            int s2 = __shfl(srcv, nb + 2);
            int s3 = __shfl(srcv, nb + 3);
            int s4 = __shfl(srcv, nb + 4);
            int s5 = __shfl(srcv, nb + 5);
            int s6 = __shfl(srcv, nb + 6);
            int s7 = __shfl(srcv, nb + 7);
            uint2 v0 = *(const uint2*)(t1f8 + (size_t)s0 * 64 + f * 8);
            uint2 v1 = *(const uint2*)(t1f8 + (size_t)s1 * 64 + f * 8);
            uint2 v2 = *(const uint2*)(t1f8 + (size_t)s2 * 64 + f * 8);
            uint2 v3 = *(const uint2*)(t1f8 + (size_t)s3 * 64 + f * 8);
            uint2 v4 = *(const uint2*)(t1f8 + (size_t)s4 * 64 + f * 8);
            uint2 v5 = *(const uint2*)(t1f8 + (size_t)s5 * 64 + f * 8);
            uint2 v6 = *(const uint2*)(t1f8 + (size_t)s6 * 64 + f * 8);
            uint2 v7 = *(const uint2*)(t1f8 + (size_t)s7 * 64 + f * 8);
            accum_fp8x8(a0, v0);
            accum_fp8x8(a1, v1);
            accum_fp8x8(a2, v2);
            accum_fp8x8(a3, v3);
            accum_fp8x8(a0, v4);
            accum_fp8x8(a1, v5);
            accum_fp8x8(a2, v6);
            accum_fp8x8(a3, v7);
        } else {
            for (int i = 0; i < cnt; ++i) {
                int s0 = __shfl(srcv, nb + i);
                accum_fp8x8(a0, *(const uint2*)(t1f8 + (size_t)s0 * 64 + f * 8));
            }
        }
        srcv = nsrcv;
    }
    #pragma unroll
    for (int i = 0; i < 8; ++i) a0[i] = (a0[i] + a1[i]) + (a2[i] + a3[i]);

    // ---- epilogue: features fe = f*8 + i ----
    const float inv = 1.0f / fmaxf((float)(e - b), 1.0f);
    const int f0 = f * 8;
    uint4 rv = *(const uint4*)(r1bf + (size_t)node * 64 + f0);
    unsigned int rw[4] = {rv.x, rv.y, rv.z, rv.w};
    float l0 = 0.f, l1 = 0.f;
    #pragma unroll
    for (int i = 0; i < 8; ++i) {
        int fe = f0 + i;
        unsigned int wv = rw[i >> 1];
        float rr = (i & 1) ? __builtin_bit_cast(float, wv)          // hi bf16, unmasked
                           : __builtin_bit_cast(float, wv << 16);
        float pre = a0[i] * inv + rr;             // b2l folded into r1
        float s   = g2[fe] * rsqrtf(v2[fe] + BN_EPS);
        float h2  = fmaxf((pre - m2[fe]) * s + be2[fe], 0.0f);
        l0 = fmaf(h2, Wc[fe * 2 + 0], l0);
        l1 = fmaf(h2, Wc[fe * 2 + 1], l1);
    }
    #pragma unroll
    for (int off = 4; off > 0; off >>= 1) {
        l0 += __shfl_xor(l0, off);
        l1 += __shfl_xor(l1, off);
    }
    if (f == 0) {
        out[(size_t)node * 2 + 0] = l0 + bc[0];
        out[(size_t)node * 2 + 1] = l1 + bc[1];
    }
}

// ---------------------------------------------------------------------------
extern "C" void kernel_launch(void* const* d_in, const int* in_sizes, int n_in,
                              void* d_out, int out_size, void* d_ws, size_t ws_size,
                              hipStream_t stream)
{
    const float* x    = (const float*)d_in[0];
    const int*   eidx = (const int*)d_in[1];   // [2, E]: row 0 = src, row 1 = dst
    const float* W1l  = (const float*)d_in[2];
    const float* b1l  = (const float*)d_in[3];
    const float* W1r  = (const float*)d_in[4];
    const float* W2l  = (const float*)d_in[5];
    const float* b2l  = (const float*)d_in[6];
    const float* W2r  = (const float*)d_in[7];
    const float* g1   = (const float*)d_in[8];
    const float* be1  = (const float*)d_in[9];
    const float* m1   = (const float*)d_in[10];
    const float* v1   = (const float*)d_in[11];
    const float* g2   = (const float*)d_in[12];
    const float* be2  = (const float*)d_in[13];
    const float* m2   = (const float*)d_in[14];
    const float* v2   = (const float*)d_in[15];
    const float* Wc   = (const float*)d_in[16];
    const float* bc   = (const float*)d_in[17];
    float* out = (float*)d_out;

    const int* src = eidx;
    const int* dst = eidx + N_EDGES;

    // ---- workspace layout ----
    char* ws = (char*)d_ws;
    size_t off = 0;
    auto alloc = [&](size_t bytes) { void* p = ws + off; off = (off + bytes + 255) & ~(size_t)255; return p; };
    int* bucketTotal  = (int*)alloc((size_t)NB * 4);
    int* bucketStart  = (int*)alloc((size_t)(NB + 1) * 4);
    int* perBlockBase = (int*)alloc((size_t)BIN_BLOCKS * NB * 4);
    unsigned int* binned = (unsigned int*)alloc((size_t)N_EDGES * 4);
    int* sortedSrc    = (int*)alloc((size_t)N_EDGES * 4);
    int* rowStart     = (int*)alloc((size_t)(N_NODES + 1) * 4);
    unsigned short* Wf1  = (unsigned short*)alloc(128 * 128 * 2);
    unsigned short* Wf2  = (unsigned short*)alloc(128 * 128 * 2);
    unsigned short* xbf  = (unsigned short*)alloc((size_t)N_NODES * 64 * 2);
    unsigned char*  x8   = (unsigned char*)alloc((size_t)N_NODES * 64);
    unsigned char*  t1f8 = (unsigned char*)alloc((size_t)N_NODES * 64);
    unsigned short* r1bf = (unsigned short*)alloc((size_t)N_NODES * 64 * 2);

    const int gemmGrid    = (N_NODES + 63) / 64;             // 1563
    const int gatherGrid  = (N_NODES * 8) / 256;             // 3125 (8 lanes/node)

    // ---- prep (wfrag + cast + zero bucketTotal in one kernel) ----
    prep_all<<<16 + CAST_BLOCKS + 1, 256, 0, stream>>>(
        x, W1l, W1r, W2l, W2r, Wf1, Wf2, xbf, x8, bucketTotal);

    // ---- counting sort of edges by dst ----
    bin_count  <<<BIN_BLOCKS, 256, 0, stream>>>(dst, bucketTotal, perBlockBase);
    bucket_scan<<<1, 1024, 0, stream>>>(bucketTotal, bucketStart);
    bin_write  <<<BIN_BLOCKS, 256, 0, stream>>>(src, dst, bucketStart, perBlockBase, binned);
    bucket_sort<<<NB, 256, 0, stream>>>(binned, bucketStart, sortedSrc, rowStart);

    // ---- fused: gather1 (in-LDS mean) + GEMM1 + bn1/relu + GEMM2 ----
    gemm_fused_g<<<gemmGrid, 256, 0, stream>>>(
        rowStart, sortedSrc, x8, xbf, Wf1, Wf2,
        b1l, g1, be1, m1, v1, b2l, t1f8, r1bf);

    // ---- layer 2: gather fp8 t1 + fused BN2/ReLU/classifier -> out ----
    gather2_e<<<gatherGrid, 256, 0, stream>>>(
        t1f8, rowStart, sortedSrc, r1bf, g2, be2, m2, v2, Wc, bc, out);
}

// Round 21
// 132.738 us; speedup vs baseline: 1.4566x; 1.0286x over previous
//
#include <hip/hip_runtime.h>
#include <math.h>

#define N_NODES 100000
#define IN_DIM 64
#define HID 128
#define HID2 64
#define N_EDGES 1600000
#define BN_EPS 1e-5f

// bucketing: 128 dst nodes per bucket
#define NPB 128
#define NB 782            // ceil(100000/128)
#define BIN_BLOCKS 391
#define BIN_CHUNK 4096    // 391*4096 >= 1.6M
#define SORT_CAP 4096     // bucket capacity for LDS sort (mean 2048, sigma ~45)
#define CAST_BLOCKS 6250  // N_NODES*16/256

typedef __attribute__((ext_vector_type(8))) __bf16 bf16x8;
typedef __attribute__((ext_vector_type(4))) float f32x4;
typedef __attribute__((ext_vector_type(2))) float f32x2;
typedef __attribute__((ext_vector_type(8))) unsigned short u16x8;

__device__ __forceinline__ unsigned short f2bf(float f) {
    unsigned int u = __builtin_bit_cast(unsigned int, f);
    u += 0x7fffu + ((u >> 16) & 1u);          // round-to-nearest-even
    return (unsigned short)(u >> 16);
}

// accumulate 8 fp8 e4m3 (one uint2) into 8 fp32 via HW converter
__device__ __forceinline__ void accum_fp8x8(float a[8], uint2 v) {
    f32x2 p0 = __builtin_amdgcn_cvt_pk_f32_fp8((int)v.x, false);
    f32x2 p1 = __builtin_amdgcn_cvt_pk_f32_fp8((int)v.x, true);
    f32x2 p2 = __builtin_amdgcn_cvt_pk_f32_fp8((int)v.y, false);
    f32x2 p3 = __builtin_amdgcn_cvt_pk_f32_fp8((int)v.y, true);
    a[0] += p0.x; a[1] += p0.y; a[2] += p1.x; a[3] += p1.y;
    a[4] += p2.x; a[5] += p2.y; a[6] += p3.x; a[7] += p3.y;
}

// accumulate 16 fp8 e4m3 (one uint4) into 16 fp32
__device__ __forceinline__ void accum_fp8x16(float a[16], uint4 v) {
    unsigned int w[4] = {v.x, v.y, v.z, v.w};
    #pragma unroll
    for (int k = 0; k < 4; ++k) {
        f32x2 lo = __builtin_amdgcn_cvt_pk_f32_fp8((int)w[k], false);
        f32x2 hi = __builtin_amdgcn_cvt_pk_f32_fp8((int)w[k], true);
        a[4*k+0] += lo.x; a[4*k+1] += lo.y;
        a[4*k+2] += hi.x; a[4*k+3] += hi.y;
    }
}

// ---------------------------------------------------------------------------
// prep_all: one kernel for all prep work.
//   blocks [0,16):              pack W1c/W2c into bf16 MFMA B-fragment order
//   blocks [16,16+CAST_BLOCKS): cast x -> bf16 (xbf) AND fp8 (x8 table)
//   last block:                 zero bucketTotal
// ---------------------------------------------------------------------------
__global__ __launch_bounds__(256) void prep_all(
    const float* __restrict__ x,
    const float* __restrict__ W1l, const float* __restrict__ W1r,
    const float* __restrict__ W2l, const float* __restrict__ W2r,
    unsigned short* __restrict__ Wf1, unsigned short* __restrict__ Wf2,
    unsigned short* __restrict__ xbf,    // [N,64] bf16
    unsigned char* __restrict__ x8,      // [N,64] fp8
    int* __restrict__ bucketTotal)
{
    const int bid = blockIdx.x;
    if (bid < 16) {
        int task = bid * 4 + (threadIdx.x >> 6);   // 0..63
        int lane = threadIdx.x & 63;
        int m  = task >> 5;          // 0: W1c, 1: W2c
        int nt = (task >> 2) & 7;
        int kt = task & 3;
        int col = nt * 16 + (lane & 15);
        int k0  = kt * 32 + (lane >> 4) * 8;
        unsigned short tmp[8];
        #pragma unroll
        for (int e = 0; e < 8; ++e) {
            int k = k0 + e;
            float v;
            if (m == 0) v = (k < 64) ? W1l[k * HID + col] : W1r[(k - 64) * HID + col];
            else        v = (col < 64) ? W2l[k * HID2 + col] : W2r[k * HID2 + (col - 64)];
            tmp[e] = f2bf(v);
        }
        unsigned short* dst = ((m == 0) ? Wf1 : Wf2)
                            + ((size_t)((nt * 4 + kt) * 64 + lane)) * 8;
        *(u16x8*)dst = *(const u16x8*)tmp;
    } else if (bid < 16 + CAST_BLOCKS) {
        int tid = (bid - 16) * 256 + threadIdx.x;      // one per 4 elements
        int node = tid >> 4;
        int q    = tid & 15;
        float4 v = ((const float4*)x)[tid];
        unsigned short o[4] = {f2bf(v.x), f2bf(v.y), f2bf(v.z), f2bf(v.w)};
        *(uint2*)(xbf + (size_t)node * 64 + q * 4) = *(const uint2*)o;
        int p = __builtin_amdgcn_cvt_pk_fp8_f32(v.x, v.y, 0, false);
        p     = __builtin_amdgcn_cvt_pk_fp8_f32(v.z, v.w, p, true);
        *(unsigned int*)(x8 + (size_t)node * 64 + q * 4) = (unsigned int)p;
    } else {
        for (int i = threadIdx.x; i < NB; i += 256) bucketTotal[i] = 0;
    }
}

// ---------------------------------------------------------------------------
// Binning pass 1: per-block bucket histogram (int4 edge reads).
// ---------------------------------------------------------------------------
__global__ __launch_bounds__(256) void bin_count(
    const int* __restrict__ dst,
    int* __restrict__ bucketTotal,     // [NB] (zeroed by prep_all)
    int* __restrict__ perBlockBase)    // [BIN_BLOCKS*NB]
{
    __shared__ int cnt[NB];
    const int t = threadIdx.x;
    for (int i = t; i < NB; i += 256) cnt[i] = 0;
    __syncthreads();
    const int e40 = blockIdx.x * (BIN_CHUNK / 4);
    const int4* dst4 = (const int4*)dst;
    #pragma unroll
    for (int i = 0; i < BIN_CHUNK / 4 / 256; ++i) {
        int ei = e40 + i * 256 + t;
        if (ei < N_EDGES / 4) {
            int4 d = dst4[ei];
            atomicAdd(&cnt[d.x >> 7], 1);
            atomicAdd(&cnt[d.y >> 7], 1);
            atomicAdd(&cnt[d.z >> 7], 1);
            atomicAdd(&cnt[d.w >> 7], 1);
        }
    }
    __syncthreads();
    for (int b = t; b < NB; b += 256) {
        int c = cnt[b];
        if (c) perBlockBase[blockIdx.x * NB + b] = atomicAdd(&bucketTotal[b], c);
    }
}

// ---------------------------------------------------------------------------
// Binning pass 2: exclusive scan of the 782 bucket totals (one block)
// ---------------------------------------------------------------------------
__global__ __launch_bounds__(1024) void bucket_scan(
    const int* __restrict__ bucketTotal, int* __restrict__ bucketStart)
{
    __shared__ int s[1024];
    const int t = threadIdx.x;
    int v = (t < NB) ? bucketTotal[t] : 0;
    s[t] = v;
    __syncthreads();
    #pragma unroll
    for (int off = 1; off < 1024; off <<= 1) {
        int u = (t >= off) ? s[t - off] : 0;
        __syncthreads();
        s[t] += u;
        __syncthreads();
    }
    if (t < NB) bucketStart[t] = s[t] - v;
    if (t == 0) bucketStart[NB] = N_EDGES;
}

// ---------------------------------------------------------------------------
// Binning pass 3: write packed (src<<7 | localDst) into bucket-grouped order
// ---------------------------------------------------------------------------
__global__ __launch_bounds__(256) void bin_write(
    const int* __restrict__ src, const int* __restrict__ dst,
    const int* __restrict__ bucketStart,
    const int* __restrict__ perBlockBase,
    unsigned int* __restrict__ binned)   // [E]
{
    __shared__ int cur[NB];
    const int t = threadIdx.x;
    for (int i = t; i < NB; i += 256) cur[i] = 0;
    __syncthreads();
    const int e40 = blockIdx.x * (BIN_CHUNK / 4);
    const int4* dst4 = (const int4*)dst;
    const int4* src4 = (const int4*)src;
    #pragma unroll
    for (int i = 0; i < BIN_CHUNK / 4 / 256; ++i) {
        int ei = e40 + i * 256 + t;
        if (ei < N_EDGES / 4) {
            int4 d = dst4[ei];
            int4 s = src4[ei];
            int ds[4] = {d.x, d.y, d.z, d.w};
            int ss[4] = {s.x, s.y, s.z, s.w};
            #pragma unroll
            for (int k = 0; k < 4; ++k) {
                int b = ds[k] >> 7;
                int pos = bucketStart[b] + perBlockBase[blockIdx.x * NB + b]
                        + atomicAdd(&cur[b], 1);
                binned[pos] = ((unsigned int)ss[k] << 7) | (unsigned int)(ds[k] & 127);
            }
        }
    }
}

// ---------------------------------------------------------------------------
// bucket_sort: one block per bucket. Stage packed edges in LDS, 128-bin
// histogram + scan -> rowStart, then local scatter -> sortedSrc.
// ---------------------------------------------------------------------------
__global__ __launch_bounds__(256) void bucket_sort(
    const unsigned int* __restrict__ binned,
    const int* __restrict__ bucketStart,
    int* __restrict__ sortedSrc,      // [E]
    int* __restrict__ rowStart)       // [N+1]
{
    __shared__ unsigned int stage[SORT_CAP];
    __shared__ int hist[NPB];
    __shared__ int cur[NPB];

    const int b  = blockIdx.x;
    const int t  = threadIdx.x;
    const int bs = bucketStart[b];
    const int be = bucketStart[b + 1];
    const int total = be - bs;

    if (t < NPB) hist[t] = 0;
    __syncthreads();

    if (total <= SORT_CAP) {
        for (int i = t; i < total; i += 256) {
            unsigned int p = binned[bs + i];
            stage[i] = p;
            atomicAdd(&hist[p & 127], 1);
        }
        __syncthreads();
        int orig = (t < NPB) ? hist[t] : 0;
        __syncthreads();
        #pragma unroll
        for (int off = 1; off < NPB; off <<= 1) {
            int v = (t < NPB && t >= off) ? hist[t - off] : 0;
            __syncthreads();
            if (t < NPB) hist[t] += v;
            __syncthreads();
        }
        if (t < NPB) {
            int excl = hist[t] - orig;
            int node = b * NPB + t;
            if (node < N_NODES) rowStart[node] = bs + excl;
            cur[t] = excl;
        }
        if (b == 0 && t == 0) rowStart[N_NODES] = N_EDGES;
        __syncthreads();
        for (int i = t; i < total; i += 256) {
            unsigned int p = stage[i];
            int pos = atomicAdd(&cur[p & 127], 1);
            sortedSrc[bs + pos] = (int)(p >> 7);
        }
    } else {
        for (int i = t; i < total; i += 256)
            atomicAdd(&hist[binned[bs + i] & 127], 1);
        __syncthreads();
        int orig = (t < NPB) ? hist[t] : 0;
        __syncthreads();
        #pragma unroll
        for (int off = 1; off < NPB; off <<= 1) {
            int v = (t < NPB && t >= off) ? hist[t - off] : 0;
            __syncthreads();
            if (t < NPB) hist[t] += v;
            __syncthreads();
        }
        if (t < NPB) {
            int excl = hist[t] - orig;
            int node = b * NPB + t;
            if (node < N_NODES) rowStart[node] = bs + excl;
            cur[t] = excl;
        }
        if (b == 0 && t == 0) rowStart[N_NODES] = N_EDGES;
        __syncthreads();
        for (int i = t; i < total; i += 256) {
            unsigned int p = binned[bs + i];
            int pos = atomicAdd(&cur[p & 127], 1);
            sortedSrc[bs + pos] = (int)(p >> 7);
        }
    }
}

// ---------------------------------------------------------------------------
// gemm_fused_g: gather1 fused into the GEMM stage-A (4 lanes/node, lane owns
// 16 features via one fp8 uint4 = 16 edges/load-instr). Mean -> LDS only.
// Then GEMM1 -> bn1/relu -> GEMM2 -> t1 fp8 / r1 bf16(+b2l).
// launch_bounds(256,4): 56 VGPR, no spills. ((256,8) spilled: 3x FETCH.)
// ---------------------------------------------------------------------------
__global__ __launch_bounds__(256, 4) void gemm_fused_g(
    const int* __restrict__ rowStart,
    const int* __restrict__ sortedSrc,
    const unsigned char* __restrict__ x8,      // [N,64] fp8
    const unsigned short* __restrict__ xbf,    // [N,64] bf16
    const unsigned short* __restrict__ Wf1,
    const unsigned short* __restrict__ Wf2,
    const float* __restrict__ b1l,
    const float* __restrict__ g1, const float* __restrict__ be1,
    const float* __restrict__ m1, const float* __restrict__ v1,
    const float* __restrict__ b2l,
    unsigned char* __restrict__ t1f8,          // [N,64] fp8 e4m3
    unsigned short* __restrict__ r1bf)         // [N,64] bf16 (h1@W2r + b2l)
{
    __shared__ unsigned short Al[64 * 136];    // row stride 272B (17x16B)

    const int t = threadIdx.x;
    const int w = t >> 6, l = t & 63;
    const int n0 = blockIdx.x * 64;
    const int r   = t >> 2;          // local node 0..63
    const int sub = t & 3;           // 16-feature block
    const int gb  = l & 60;          // 4-lane group base within wave
    const int node = n0 + r;

    // ---- stage x-half (bf16) into LDS cols [64,128) ----
    {
        unsigned short* drow = &Al[r * 136 + 64 + sub * 16];
        if (node < N_NODES) {
            const uint4* sp = (const uint4*)(xbf + (size_t)node * 64 + sub * 16);
            uint4 v0 = sp[0], v1 = sp[1];
            *(uint4*)drow = v0;
            *(uint4*)(drow + 8) = v1;
        } else {
            uint4 z; z.x = z.y = z.z = z.w = 0u;
            *(uint4*)drow = z;
            *(uint4*)(drow + 8) = z;
        }
    }

    // ---- gather mean from x8 -> LDS cols [0,64) ----
    {
        unsigned short* drow = &Al[r * 136 + sub * 16];
        if (node < N_NODES) {
            const int b = rowStart[node], e = rowStart[node + 1];
            float a[16] = {};
            for (int base = b; base < e; base += 4) {
                const int cnt = min(e - base, 4);            // group-uniform
                int srcv = (base + sub < e) ? sortedSrc[base + sub] : 0;
                if (cnt == 4) {
                    int s0 = __shfl(srcv, gb + 0);
                    int s1 = __shfl(srcv, gb + 1);
                    int s2 = __shfl(srcv, gb + 2);
                    int s3 = __shfl(srcv, gb + 3);
                    uint4 v0 = *(const uint4*)(x8 + (size_t)s0 * 64 + sub * 16);
                    uint4 v1 = *(const uint4*)(x8 + (size_t)s1 * 64 + sub * 16);
                    uint4 v2 = *(const uint4*)(x8 + (size_t)s2 * 64 + sub * 16);
                    uint4 v3 = *(const uint4*)(x8 + (size_t)s3 * 64 + sub * 16);
                    accum_fp8x16(a, v0);
                    accum_fp8x16(a, v1);
                    accum_fp8x16(a, v2);
                    accum_fp8x16(a, v3);
                } else {
                    for (int i = 0; i < cnt; ++i) {
                        int s0 = __shfl(srcv, gb + i);
                        uint4 v0 = *(const uint4*)(x8 + (size_t)s0 * 64 + sub * 16);
                        accum_fp8x16(a, v0);
                    }
                }
            }
            float inv = 1.0f / fmaxf((float)(e - b), 1.0f);
            unsigned short o[16];
            #pragma unroll
            for (int i = 0; i < 16; ++i) o[i] = f2bf(a[i] * inv);
            *(uint4*)drow       = *(const uint4*)o;
            *(uint4*)(drow + 8) = *(const uint4*)(o + 8);
        } else {
            uint4 z; z.x = z.y = z.z = z.w = 0u;
            *(uint4*)drow = z;
            *(uint4*)(drow + 8) = z;
        }
    }
    __syncthreads();

    const int row = l & 15, kq = l >> 4;

    // ---- GEMM1 ----
    f32x4 acc[4][2];
    #pragma unroll
    for (int a = 0; a < 4; ++a)
        #pragma unroll
        for (int b = 0; b < 2; ++b) acc[a][b] = (f32x4)(0.0f);

    #pragma unroll
    for (int kt = 0; kt < 4; ++kt) {
        bf16x8 bfr[2];
        #pragma unroll
        for (int n = 0; n < 2; ++n)
            bfr[n] = __builtin_bit_cast(bf16x8,
                *(const u16x8*)(Wf1 + ((size_t)(((2 * w + n) * 4 + kt) * 64 + l)) * 8));
        #pragma unroll
        for (int mt = 0; mt < 4; ++mt) {
            bf16x8 afr = __builtin_bit_cast(bf16x8,
                *(const u16x8*)&Al[(mt * 16 + row) * 136 + kt * 32 + kq * 8]);
            #pragma unroll
            for (int n = 0; n < 2; ++n)
                acc[mt][n] = __builtin_amdgcn_mfma_f32_16x16x32_bf16(
                    afr, bfr[n], acc[mt][n], 0, 0, 0);
        }
    }
    __syncthreads();   // all reads of A done before h1 overwrites

    // ---- epilogue 1: h1 = relu(bn1(pre)) -> Al (bf16) ----
    #pragma unroll
    for (int n = 0; n < 2; ++n) {
        int j = w * 32 + n * 16 + (l & 15);
        float s  = g1[j] * rsqrtf(v1[j] + BN_EPS);
        float of = be1[j] + (b1l[j] - m1[j]) * s;
        #pragma unroll
        for (int mt = 0; mt < 4; ++mt) {
            #pragma unroll
            for (int i = 0; i < 4; ++i) {
                float h = fmaxf(fmaf(acc[mt][n][i], s, of), 0.0f);
                Al[(mt * 16 + kq * 4 + i) * 136 + j] = f2bf(h);
            }
        }
    }
    __syncthreads();

    // ---- GEMM2 ----
    f32x4 acc2[4][2];
    #pragma unroll
    for (int a = 0; a < 4; ++a)
        #pragma unroll
        for (int b = 0; b < 2; ++b) acc2[a][b] = (f32x4)(0.0f);

    #pragma unroll
    for (int kt = 0; kt < 4; ++kt) {
        bf16x8 bfr[2];
        #pragma unroll
        for (int n = 0; n < 2; ++n)
            bfr[n] = __builtin_bit_cast(bf16x8,
                *(const u16x8*)(Wf2 + ((size_t)(((2 * w + n) * 4 + kt) * 64 + l)) * 8));
        #pragma unroll
        for (int mt = 0; mt < 4; ++mt) {
            bf16x8 afr = __builtin_bit_cast(bf16x8,
                *(const u16x8*)&Al[(mt * 16 + row) * 136 + kt * 32 + kq * 8]);
            #pragma unroll
            for (int n = 0; n < 2; ++n)
                acc2[mt][n] = __builtin_amdgcn_mfma_f32_16x16x32_bf16(
                    afr, bfr[n], acc2[mt][n], 0, 0, 0);
        }
    }

    // ---- epilogue 2: cols [0,64) -> t1 fp8 ; [64,128) -> r1 bf16 (+b2l) ----
    #pragma unroll
    for (int n = 0; n < 2; ++n) {
        int j = w * 32 + n * 16 + (l & 15);
        float bl = (w >= 2) ? b2l[j - 64] : 0.0f;
        #pragma unroll
        for (int mt = 0; mt < 4; ++mt) {
            #pragma unroll
            for (int i = 0; i < 4; ++i) {
                int nn = n0 + mt * 16 + kq * 4 + i;
                if (nn < N_NODES) {
                    float vv = acc2[mt][n][i];
                    if (w < 2) {
                        int p = __builtin_amdgcn_cvt_pk_fp8_f32(vv, vv, 0, false);
                        t1f8[(size_t)nn * 64 + j] = (unsigned char)(p & 0xff);
                    } else {
                        r1bf[(size_t)nn * 64 + (j - 64)] = f2bf(vv + bl);
                    }
                }
            }
        }
    }
}

// ---------------------------------------------------------------------------
// gather2_e: eighth-wave gather of fp8 t1 rows, 8-deep load batch in the
// full-chunk path, + fused BN2/ReLU/classifier epilogue.
// ---------------------------------------------------------------------------
__global__ __launch_bounds__(256) void gather2_e(
    const unsigned char* __restrict__ t1f8,  // [N,64] fp8 e4m3
    const int* __restrict__ rowStart,
    const int* __restrict__ sortedSrc,
    const unsigned short* __restrict__ r1bf, // [N,64] bf16
    const float* __restrict__ g2, const float* __restrict__ be2,
    const float* __restrict__ m2, const float* __restrict__ v2,
    const float* __restrict__ Wc, const float* __restrict__ bc,
    float* __restrict__ out)                 // [N,2]
{
    const int node = (int)((blockIdx.x * 256u + threadIdx.x) >> 3);
    const int lane = threadIdx.x & 63;
    const int f    = lane & 7;
    const int nb   = lane & 56;
    const int b = rowStart[node], e = rowStart[node + 1];

    float a0[8] = {}, a1[8] = {}, a2[8] = {}, a3[8] = {};

    for (int base = b; base < e; base += 8) {
        const int cnt = min(e - base, 8);                   // group-uniform
        int srcv = (base + f < e) ? sortedSrc[base + f] : 0;
        if (cnt == 8) {
            int s0 = __shfl(srcv, nb + 0);
            int s1 = __shfl(srcv, nb + 1);
            int s2 = __shfl(srcv, nb + 2);
            int s3 = __shfl(srcv, nb + 3);
            int s4 = __shfl(srcv, nb + 4);
            int s5 = __shfl(srcv, nb + 5);
            int s6 = __shfl(srcv, nb + 6);
            int s7 = __shfl(srcv, nb + 7);
            uint2 v0 = *(const uint2*)(t1f8 + (size_t)s0 * 64 + f * 8);
            uint2 v1 = *(const uint2*)(t1f8 + (size_t)s1 * 64 + f * 8);
            uint2 v2 = *(const uint2*)(t1f8 + (size_t)s2 * 64 + f * 8);
            uint2 v3 = *(const uint2*)(t1f8 + (size_t)s3 * 64 + f * 8);
            uint2 v4 = *(const uint2*)(t1f8 + (size_t)s4 * 64 + f * 8);
            uint2 v5 = *(const uint2*)(t1f8 + (size_t)s5 * 64 + f * 8);
            uint2 v6 = *(const uint2*)(t1f8 + (size_t)s6 * 64 + f * 8);
            uint2 v7 = *(const uint2*)(t1f8 + (size_t)s7 * 64 + f * 8);
            accum_fp8x8(a0, v0);
            accum_fp8x8(a1, v1);
            accum_fp8x8(a2, v2);
            accum_fp8x8(a3, v3);
            accum_fp8x8(a0, v4);
            accum_fp8x8(a1, v5);
            accum_fp8x8(a2, v6);
            accum_fp8x8(a3, v7);
        } else {
            for (int i = 0; i < cnt; ++i) {
                int s0 = __shfl(srcv, nb + i);
                accum_fp8x8(a0, *(const uint2*)(t1f8 + (size_t)s0 * 64 + f * 8));
            }
        }
    }
    #pragma unroll
    for (int i = 0; i < 8; ++i) a0[i] = (a0[i] + a1[i]) + (a2[i] + a3[i]);

    // ---- epilogue: features fe = f*8 + i ----
    const float inv = 1.0f / fmaxf((float)(e - b), 1.0f);
    const int f0 = f * 8;
    uint4 rv = *(const uint4*)(r1bf + (size_t)node * 64 + f0);
    unsigned int rw[4] = {rv.x, rv.y, rv.z, rv.w};
    float l0 = 0.f, l1 = 0.f;
    #pragma unroll
    for (int i = 0; i < 8; ++i) {
        int fe = f0 + i;
        unsigned int wv = rw[i >> 1];
        float rr = (i & 1) ? __builtin_bit_cast(float, wv)          // hi bf16, unmasked
                           : __builtin_bit_cast(float, wv << 16);
        float pre = a0[i] * inv + rr;             // b2l folded into r1
        float s   = g2[fe] * rsqrtf(v2[fe] + BN_EPS);
        float h2  = fmaxf((pre - m2[fe]) * s + be2[fe], 0.0f);
        l0 = fmaf(h2, Wc[fe * 2 + 0], l0);
        l1 = fmaf(h2, Wc[fe * 2 + 1], l1);
    }
    #pragma unroll
    for (int off = 4; off > 0; off >>= 1) {
        l0 += __shfl_xor(l0, off);
        l1 += __shfl_xor(l1, off);
    }
    if (f == 0) {
        out[(size_t)node * 2 + 0] = l0 + bc[0];
        out[(size_t)node * 2 + 1] = l1 + bc[1];
    }
}

// ---------------------------------------------------------------------------
extern "C" void kernel_launch(void* const* d_in, const int* in_sizes, int n_in,
                              void* d_out, int out_size, void* d_ws, size_t ws_size,
                              hipStream_t stream)
{
    const float* x    = (const float*)d_in[0];
    const int*   eidx = (const int*)d_in[1];   // [2, E]: row 0 = src, row 1 = dst
    const float* W1l  = (const float*)d_in[2];
    const float* b1l  = (const float*)d_in[3];
    const float* W1r  = (const float*)d_in[4];
    const float* W2l  = (const float*)d_in[5];
    const float* b2l  = (const float*)d_in[6];
    const float* W2r  = (const float*)d_in[7];
    const float* g1   = (const float*)d_in[8];
    const float* be1  = (const float*)d_in[9];
    const float* m1   = (const float*)d_in[10];
    const float* v1   = (const float*)d_in[11];
    const float* g2   = (const float*)d_in[12];
    const float* be2  = (const float*)d_in[13];
    const float* m2   = (const float*)d_in[14];
    const float* v2   = (const float*)d_in[15];
    const float* Wc   = (const float*)d_in[16];
    const float* bc   = (const float*)d_in[17];
    float* out = (float*)d_out;

    const int* src = eidx;
    const int* dst = eidx + N_EDGES;

    // ---- workspace layout ----
    char* ws = (char*)d_ws;
    size_t off = 0;
    auto alloc = [&](size_t bytes) { void* p = ws + off; off = (off + bytes + 255) & ~(size_t)255; return p; };
    int* bucketTotal  = (int*)alloc((size_t)NB * 4);
    int* bucketStart  = (int*)alloc((size_t)(NB + 1) * 4);
    int* perBlockBase = (int*)alloc((size_t)BIN_BLOCKS * NB * 4);
    unsigned int* binned = (unsigned int*)alloc((size_t)N_EDGES * 4);
    int* sortedSrc    = (int*)alloc((size_t)N_EDGES * 4);
    int* rowStart     = (int*)alloc((size_t)(N_NODES + 1) * 4);
    unsigned short* Wf1  = (unsigned short*)alloc(128 * 128 * 2);
    unsigned short* Wf2  = (unsigned short*)alloc(128 * 128 * 2);
    unsigned short* xbf  = (unsigned short*)alloc((size_t)N_NODES * 64 * 2);
    unsigned char*  x8   = (unsigned char*)alloc((size_t)N_NODES * 64);
    unsigned char*  t1f8 = (unsigned char*)alloc((size_t)N_NODES * 64);
    unsigned short* r1bf = (unsigned short*)alloc((size_t)N_NODES * 64 * 2);

    const int gemmGrid    = (N_NODES + 63) / 64;             // 1563
    const int gatherGrid  = (N_NODES * 8) / 256;             // 3125 (8 lanes/node)

    // ---- prep (wfrag + cast + zero bucketTotal in one kernel) ----
    prep_all<<<16 + CAST_BLOCKS + 1, 256, 0, stream>>>(
        x, W1l, W1r, W2l, W2r, Wf1, Wf2, xbf, x8, bucketTotal);

    // ---- counting sort of edges by dst ----
    bin_count  <<<BIN_BLOCKS, 256, 0, stream>>>(dst, bucketTotal, perBlockBase);
    bucket_scan<<<1, 1024, 0, stream>>>(bucketTotal, bucketStart);
    bin_write  <<<BIN_BLOCKS, 256, 0, stream>>>(src, dst, bucketStart, perBlockBase, binned);
    bucket_sort<<<NB, 256, 0, stream>>>(binned, bucketStart, sortedSrc, rowStart);

    // ---- fused: gather1 (in-LDS mean) + GEMM1 + bn1/relu + GEMM2 ----
    gemm_fused_g<<<gemmGrid, 256, 0, stream>>>(
        rowStart, sortedSrc, x8, xbf, Wf1, Wf2,
        b1l, g1, be1, m1, v1, b2l, t1f8, r1bf);

    // ---- layer 2: gather fp8 t1 + fused BN2/ReLU/classifier -> out ----
    gather2_e<<<gatherGrid, 256, 0, stream>>>(
        t1f8, rowStart, sortedSrc, r1bf, g2, be2, m2, v2, Wc, bc, out);
}